// Round 9
// baseline (137.027 us; speedup 1.0000x reference)
//
#include <hip/hip_runtime.h>

// GIoU loss, N=4M boxes, [N,4] f32. 128 MB pure read per call.
// Read-path ladder: cached 3.0 TB/s (R2-R4), nt 3.8 TB/s (R6-R7), mixed
// 3.8 (R8) — all insensitive to ILP/TLP/VGPR. Write-only fill does 6.5 TB/s.
// Hypothesis: the VGPR load-return path caps reads; fill has no return path.
// R9: global_load_lds (HBM->LDS DMA, no VGPR writeback, aux=NT) staging,
// compute from LDS. If flat, three distinct read paths all cap ~3.8 TB/s
// -> structural read ceiling -> roofline.

#define TPB   256
#define TILE  1024                       // boxes per block; LDS = 2*16KB

typedef float vfloat4 __attribute__((ext_vector_type(4)));

__device__ __forceinline__ float giou_term(vfloat4 p, vfloat4 t) {
    float area_p = (p.z - p.x) * (p.w - p.y);
    float area_t = (t.z - t.x) * (t.w - t.y);
    float iw = fmaxf(fminf(p.z, t.z) - fmaxf(p.x, t.x), 0.0f);
    float ih = fmaxf(fminf(p.w, t.w) - fmaxf(p.y, t.y), 0.0f);
    float inter = iw * ih;
    float uni   = area_p + area_t - inter;
    float iou   = inter / uni;
    float cw = fmaxf(p.z, t.z) - fminf(p.x, t.x);
    float ch = fmaxf(p.w, t.w) - fminf(p.y, t.y);
    float area_c = cw * ch;
    return 1.0f - (iou - (area_c - uni) / area_c);
}

__device__ __forceinline__ void load_to_lds(const vfloat4* g, vfloat4* l) {
    // HW semantics: per-lane global addr; LDS dest = wave-uniform base + lane*16.
    // aux=2 (NT bit on gfx940+) -> no L2 retention.
    __builtin_amdgcn_global_load_lds(
        (const __attribute__((address_space(1))) void*)g,
        (__attribute__((address_space(3))) void*)l,
        16, 0, 2);
}

__global__ __launch_bounds__(TPB) void giou_main_kernel(
        const vfloat4* __restrict__ pred,
        const vfloat4* __restrict__ targ,
        float* __restrict__ partials,
        int n) {
    __shared__ vfloat4 lp[TILE];
    __shared__ vfloat4 lt[TILE];

    const int base = blockIdx.x * TILE;
    const int lane = threadIdx.x & 63;
    const int wave = threadIdx.x >> 6;      // 4 waves
    float sum = 0.0f;

    if (base + TILE <= n) {
        // stage: each wave DMAs 256 boxes per array (4 x 64-box instructions)
        #pragma unroll
        for (int j = 0; j < 4; ++j) {
            int idx = wave * 256 + j * 64;           // wave-uniform
            load_to_lds(&pred[base + idx + lane], &lp[idx]);
            load_to_lds(&targ[base + idx + lane], &lt[idx]);
        }
        __syncthreads();   // drains vmcnt for the LDS-DMA

        // compute: thread i handles boxes {2i, 2i+1, 512+2i, 512+2i+1}
        // (32B stride across lanes -> 4-way LDS aliasing, 1.58x — cheap)
        int b0 = 2 * (int)threadIdx.x;
        int b1 = 512 + 2 * (int)threadIdx.x;
        sum  = giou_term(lp[b0],     lt[b0]);
        sum += giou_term(lp[b0 + 1], lt[b0 + 1]);
        sum += giou_term(lp[b1],     lt[b1]);
        sum += giou_term(lp[b1 + 1], lt[b1 + 1]);
    } else {
        // tail block (256 boxes): direct guarded loads, no LDS
        #pragma unroll
        for (int k = 0; k < 4; ++k) {
            int i = base + threadIdx.x + k * TPB;
            if (i < n) sum += giou_term(pred[i], targ[i]);
        }
        __syncthreads();
    }

    // wave reduce (wave = 64)
    #pragma unroll
    for (int off = 32; off > 0; off >>= 1)
        sum += __shfl_down(sum, off, 64);

    __shared__ float wave_sums[TPB / 64];
    if (lane == 0) wave_sums[wave] = sum;
    __syncthreads();
    if (threadIdx.x == 0) {
        partials[blockIdx.x] = wave_sums[0] + wave_sums[1]
                             + wave_sums[2] + wave_sums[3];
    }
}

__global__ __launch_bounds__(TPB) void giou_finalize_kernel(
        const float* __restrict__ partials, int nblocks,
        float* __restrict__ out, double inv_n) {
    double s = 0.0;
    for (int i = threadIdx.x; i < nblocks; i += TPB)
        s += (double)partials[i];
    #pragma unroll
    for (int off = 32; off > 0; off >>= 1)
        s += __shfl_down(s, off, 64);
    __shared__ double wave_sums[TPB / 64];
    int lane = threadIdx.x & 63;
    int wid  = threadIdx.x >> 6;
    if (lane == 0) wave_sums[wid] = s;
    __syncthreads();
    if (threadIdx.x == 0) {
        double tot = wave_sums[0] + wave_sums[1] + wave_sums[2] + wave_sums[3];
        *out = (float)(tot * inv_n);
    }
}

extern "C" void kernel_launch(void* const* d_in, const int* in_sizes, int n_in,
                              void* d_out, int out_size, void* d_ws, size_t ws_size,
                              hipStream_t stream) {
    const vfloat4* pred = (const vfloat4*)d_in[0];
    const vfloat4* targ = (const vfloat4*)d_in[1];
    float* out      = (float*)d_out;
    float* partials = (float*)d_ws;          // nblocks floats, all written
    int n = in_sizes[0] / 4;                 // 4,000,000 boxes
    int nblocks = (n + TILE - 1) / TILE;     // 3907

    giou_main_kernel<<<nblocks, TPB, 0, stream>>>(pred, targ, partials, n);
    giou_finalize_kernel<<<1, TPB, 0, stream>>>(partials, nblocks, out,
                                                1.0 / (double)n);
}